// Round 3
// baseline (67.204 us; speedup 1.0000x reference)
//
#include <hip/hip_runtime.h>
#include <math.h>

// Problem constants (fixed by reference): B=256 batches, N=M=256 points, D=4.
#define BB 256
#define NN 256
#define MM 256

#define POISON  1.0e18f   // invalid-point coordinate: dist^2 ~ 4e36, finite, loses every min
#define MINSENT 3.0e38f

typedef float f2 __attribute__((ext_vector_type(2)));
__device__ __forceinline__ f2 splat2(float v) { f2 r; r.x = v; r.y = v; return r; }

// Kernel 1: TWO blocks per batch (one per chamfer direction), 512 threads each.
//   R2 lesson: kernel 1 is phase-latency-bound (stage -> barrier -> min-pass ->
//   barrier -> epilogue), not pipe-bound. With one 1024-thread block per CU the
//   barriers idle all 16 waves. Splitting into 2 independent 512-thread blocks
//   per batch puts 2 blocks on each CU: one block's staging overlaps the
//   other's min-pass, and each barrier only syncs 8 waves. Per-CU VALU/LDS
//   work is unchanged; staging duplication is ~10 KB/batch (trivial).
//   d=0: rows pass (X->R scan), record (sum_xy, sum||x||_nz, nx)
//   d=1: cols pass (R->X scan), record (sum_yx, sum||y||_zero, ny)
//   Min-pass math identical to R2: K=8 own rows x 16-wide scanned chunk,
//   dist^2 = h_own + (|y|^2 - 2 x.y), scan |y|^2 recomputed in-register,
//   own |x|^2 hoisted out of the min. Packed fp32 (v_pk_fma_f32) throughout.
__global__ __launch_bounds__(512) void chamfer_batch_kernel(
    const float* __restrict__ target,   // [B, N, 4]
    const float* __restrict__ reco,     // [B, M, 4]
    const int*   __restrict__ in_pid,   // [B, N]
    const int*   __restrict__ out_pid,  // [B, M]
    float4* __restrict__ ws)            // [2][B] per-direction records
{
    const int b = blockIdx.x >> 1;
    const int d = blockIdx.x & 1;       // 0: rows (X->R), 1: cols (R->X)
    const int t = threadIdx.x;          // 0..511

    __shared__ __align__(16) float sOx[256], sOy[256], sOz[256], sOw[256], sOh[256]; // own planes, 5 KB
    __shared__ __align__(16) float sSx[256], sSy[256], sSz[256], sSw[256];           // scan planes, 4 KB
    __shared__ float sOn[256];                        // own RAW norms (cols pass), 1 KB
    __shared__ int   sMo[256];                        // own mask, 1 KB
    __shared__ float pmin[16][256];                   // chunk-min partials, 16 KB
    __shared__ int   cnt[4];                          // per-wave popcounts (waves 0..3)
    __shared__ float wred[4][2];                      // wave-reduction slots

    const float* ownBase  = d ? (reco   + (size_t)b * MM * 4) : (target + (size_t)b * NN * 4);
    const float* scanBase = d ? (target + (size_t)b * NN * 4) : (reco   + (size_t)b * MM * 4);
    const int*   ownPid   = d ? (out_pid + b * MM) : (in_pid  + b * NN);
    const int*   scanPid  = d ? (in_pid  + b * NN) : (out_pid + b * MM);

    // ---- stage: threads 0..255 own side, 256..511 scan side ----
    if (t < 256) {
        const int i = t;
        const float4 p = ((const float4*)ownBase)[i];
        const int m = (ownPid[i] != 0);
        const float rawsq = fmaf(p.x, p.x, fmaf(p.y, p.y, fmaf(p.z, p.z, p.w * p.w)));
        const float4 pp = m ? p : make_float4(POISON, POISON, POISON, POISON);
        sOx[i] = pp.x; sOy[i] = pp.y; sOz[i] = pp.z; sOw[i] = pp.w;
        sOh[i] = m ? rawsq : (4.0f * POISON * POISON);
        sOn[i] = sqrtf(rawsq);
        sMo[i] = m;
        const unsigned long long bal = __ballot(m);   // waves 0..3 fully active here
        if ((t & 63) == 0) cnt[t >> 6] = (int)__popcll(bal);
    } else {
        const int i = t - 256;
        const float4 p = ((const float4*)scanBase)[i];
        const int m = (scanPid[i] != 0);
        const float4 pp = m ? p : make_float4(POISON, POISON, POISON, POISON);
        sSx[i] = pp.x; sSy[i] = pp.y; sSz[i] = pp.z; sSw[i] = pp.w;
    }
    __syncthreads();

    // ---- packed-math min pass: K=8 own rows x 16-wide scanned chunk ----
    {
        const int c = t >> 5;           // 0..15 scanned chunk (uniform per half-wave)
        const int g = t & 31;           // own rows g + 32k, k=0..7

        f2 n2x[8], n2y[8], n2z[8], n2w[8], mn[8];
        #pragma unroll
        for (int k = 0; k < 8; ++k) {
            const int row = g + (k << 5);
            n2x[k] = splat2(-2.f * sOx[row]);
            n2y[k] = splat2(-2.f * sOy[row]);
            n2z[k] = splat2(-2.f * sOz[row]);
            n2w[k] = splat2(-2.f * sOw[row]);
            mn[k]  = splat2(MINSENT);
        }

        const int base = c << 4;        // 16-wide scanned chunk
        #pragma unroll
        for (int q = 0; q < 4; ++q) {   // 4 scanned points per iteration
            const int o = base + (q << 2);
            const float4 rx4 = *(const float4*)&sSx[o];
            const float4 ry4 = *(const float4*)&sSy[o];
            const float4 rz4 = *(const float4*)&sSz[o];
            const float4 rw4 = *(const float4*)&sSw[o];
            f2 rx0, rx1, ry0, ry1, rz0, rz1, rw0, rw1;
            rx0.x = rx4.x; rx0.y = rx4.y;  rx1.x = rx4.z; rx1.y = rx4.w;
            ry0.x = ry4.x; ry0.y = ry4.y;  ry1.x = ry4.z; ry1.y = ry4.w;
            rz0.x = rz4.x; rz0.y = rz4.y;  rz1.x = rz4.z; rz1.y = rz4.w;
            rw0.x = rw4.x; rw0.y = rw4.y;  rw1.x = rw4.z; rw1.y = rw4.w;
            // scan-side |y|^2, recomputed (cheaper than an LDS h-plane read)
            f2 rh0 = rx0 * rx0;
            rh0 = __builtin_elementwise_fma(ry0, ry0, rh0);
            rh0 = __builtin_elementwise_fma(rz0, rz0, rh0);
            rh0 = __builtin_elementwise_fma(rw0, rw0, rh0);
            f2 rh1 = rx1 * rx1;
            rh1 = __builtin_elementwise_fma(ry1, ry1, rh1);
            rh1 = __builtin_elementwise_fma(rz1, rz1, rh1);
            rh1 = __builtin_elementwise_fma(rw1, rw1, rh1);
            #pragma unroll
            for (int k = 0; k < 8; ++k) {
                // s = |y|^2 - 2 x.y   (own |x|^2 added once in the epilogue)
                f2 a0 = __builtin_elementwise_fma(n2x[k], rx0, rh0);
                a0 = __builtin_elementwise_fma(n2y[k], ry0, a0);
                a0 = __builtin_elementwise_fma(n2z[k], rz0, a0);
                a0 = __builtin_elementwise_fma(n2w[k], rw0, a0);
                mn[k] = __builtin_elementwise_min(mn[k], a0);
                f2 a1 = __builtin_elementwise_fma(n2x[k], rx1, rh1);
                a1 = __builtin_elementwise_fma(n2y[k], ry1, a1);
                a1 = __builtin_elementwise_fma(n2z[k], rz1, a1);
                a1 = __builtin_elementwise_fma(n2w[k], rw1, a1);
                mn[k] = __builtin_elementwise_min(mn[k], a1);
            }
        }
        #pragma unroll
        for (int k = 0; k < 8; ++k)
            pmin[c][g + (k << 5)] = fminf(mn[k].x, mn[k].y);
    }
    __syncthreads();

    // ---- epilogue: threads 0..255, one own row each ----
    if (t < 256) {
        const int i = t;
        float m = pmin[0][i];
        #pragma unroll
        for (int c2 = 1; c2 < 16; ++c2) m = fminf(m, pmin[c2][i]);
        m = fmaxf(sOh[i] + m, 0.0f);                 // dist^2; guard rounding negatives
        const int msk = sMo[i];
        const float va = msk ? sqrtf(m) : 0.f;       // -> sum_xy (d=0) / sum_yx (d=1)
        const float vb = (d == 0) ? (msk ? sqrtf(sOh[i]) : 0.f)   // sum ||x|| nonzero pid
                                  : (msk ? 0.f : sOn[i]);          // sum ||y|| zero pid
        float a = va, z = vb;
        #pragma unroll
        for (int off = 32; off > 0; off >>= 1) {
            a += __shfl_down(a, off, 64);
            z += __shfl_down(z, off, 64);
        }
        if ((t & 63) == 0) {
            wred[t >> 6][0] = a;
            wred[t >> 6][1] = z;
        }
    }
    __syncthreads();

    if (t == 0) {
        float sa = 0.f, sb = 0.f;
        int n = 0;
        #pragma unroll
        for (int w = 0; w < 4; ++w) {
            sa += wred[w][0];
            sb += wred[w][1];
            n  += cnt[w];
        }
        ws[d * BB + b] = make_float4(sa, sb, (float)n, 0.f);  // plain store, no atomics
    }
}

// Kernel 2: one wave combines the per-direction records and reduces 256
// batches. Summation structure kept IDENTICAL to the previous passing version
// (4 sequential k-adds then shfl tree) so the result stays bit-exact.
__global__ __launch_bounds__(64) void chamfer_final_kernel(
    const float4* __restrict__ ws, float* __restrict__ out)
{
    const int t = threadIdx.x;   // 0..63
    float a = 0.f, z = 0.f;
    #pragma unroll
    for (int k = 0; k < 4; ++k) {
        const int bb = t + (k << 6);
        const float4 r0 = ws[bb];         // rows record: (s_xy, s_nx, nx)
        const float4 r1 = ws[BB + bb];    // cols record: (s_yx, s_ny0, ny)
        const int nx = (int)r0.z, ny = (int)r1.z;
        const float n_in  = (float)max(1, nx);
        const float n_out = (float)max(1, ny);
        const float normal = 0.5f * (r0.x / n_out + r1.x / n_in);
        const float eucl_nz = (ny == 0) ? (r0.y / n_in)
                                        : ((nx == 0) ? 0.0f : normal);
        const float n_zero = (float)max(1, MM - ny);
        a += eucl_nz;
        z += r1.y / n_zero;
    }
    #pragma unroll
    for (int off = 32; off > 0; off >>= 1) {
        a += __shfl_down(a, off, 64);
        z += __shfl_down(z, off, 64);
    }
    if (t == 0) {
        out[0] = a * (1.0f / BB);
        out[1] = z * (1.0f / BB);
    }
}

extern "C" void kernel_launch(void* const* d_in, const int* in_sizes, int n_in,
                              void* d_out, int out_size, void* d_ws, size_t ws_size,
                              hipStream_t stream) {
    const float* target  = (const float*)d_in[0];
    const float* reco    = (const float*)d_in[1];
    const int*   in_pid  = (const int*)d_in[2];
    const int*   out_pid = (const int*)d_in[3];
    float* out = (float*)d_out;
    float4* ws = (float4*)d_ws;

    chamfer_batch_kernel<<<dim3(2 * BB), dim3(512), 0, stream>>>(
        target, reco, in_pid, out_pid, ws);
    chamfer_final_kernel<<<dim3(1), dim3(64), 0, stream>>>(ws, out);
}

// Round 4
// 66.374 us; speedup vs baseline: 1.0125x; 1.0125x over previous
//
#include <hip/hip_runtime.h>
#include <math.h>

// Problem constants (fixed by reference): B=256 batches, N=M=256 points, D=4.
#define BB 256
#define NN 256
#define MM 256

#define POISON  1.0e18f   // invalid-point coordinate: keeps dist^2 ~ 4e36, finite, loses every min
#define MINSENT 3.0e38f

typedef float f2 __attribute__((ext_vector_type(2)));
__device__ __forceinline__ f2 splat2(float v) { f2 r; r.x = v; r.y = v; return r; }

// Kernel 1: one block per batch, 1024 threads.  (R2 configuration — best
// measured of: R0 K=4/C=32 base 67.0; R1 last-block fusion 70.9 (serialized
// cross-XCD tail); R2 this 66.5; R3 2-blocks-per-batch split 67.2 (doubled
// staging traffic + dispatch count cancelled the phase overlap).)
//   staging : threads 0..511 stage SoA planes (x,y,z,w,|p|^2), poisoned, masks,
//             raw reco norms.
//   passes  : threads 0..511 row-mins (X->R), 512..1023 col-mins (R->X).
//             K=8 own rows per thread x one 16-wide scanned chunk (C=16).
//             Scan reads per wave 16 (scan |y|^2 recomputed in-register, own
//             |x|^2 hoisted out of the min: min_j(hx+s_j) = hx + min_j s_j).
//             dist^2 = hx + (|y|^2 - 2 x.y), packed fp32 two-scan-points-wide.
//   epilogue: threads 0..511 combine 16 chunk-mins per row/col, add own |x|^2,
//             wave-reduce, thread 0 plain-stores the batch pair to ws[b].
__global__ __launch_bounds__(1024) void chamfer_batch_kernel(
    const float* __restrict__ target,   // [B, N, 4]
    const float* __restrict__ reco,     // [B, M, 4]
    const int*   __restrict__ in_pid,   // [B, N]
    const int*   __restrict__ out_pid,  // [B, M]
    float2* __restrict__ ws)            // [B] per-batch (eucl_nonzero, eucl_zero)
{
    const int b = blockIdx.x;
    const int t = threadIdx.x;   // 0..1023

    __shared__ __align__(16) float sTx[NN], sTy[NN], sTz[NN], sTw[NN], sTh[NN]; // SoA, 5 KB
    __shared__ __align__(16) float sRx[MM], sRy[MM], sRz[MM], sRw[MM], sRh[MM]; // SoA, 5 KB
    __shared__ float sRn[MM];                         // RAW reco norms, 1 KB
    __shared__ int   sMx[NN], sMy[MM];                // masks, 2 KB
    __shared__ float pmin1[16][NN], pmin2[16][MM];    // chunk-min partials, 32 KB
    __shared__ int   cnt[8];                          // per-wave popcounts
    __shared__ float wred[8][2];                      // wave-reduction slots

    // ---- stage: threads 0..255 target, 256..511 reco ----
    if (t < 512) {
        const bool isT = (t < 256);
        const int  i   = isT ? t : (t - 256);
        const float4* src = isT ? (const float4*)(target + (size_t)b * NN * 4)
                                : (const float4*)(reco   + (size_t)b * MM * 4);
        const int*    pid = isT ? (in_pid + b * NN) : (out_pid + b * MM);
        float4 p = src[i];
        const int m = (pid[i] != 0);
        const float rawsq = fmaf(p.x, p.x, fmaf(p.y, p.y, fmaf(p.z, p.z, p.w * p.w)));
        float4 pp = m ? p : make_float4(POISON, POISON, POISON, POISON);
        const float ppsq = m ? rawsq : (4.0f * POISON * POISON);
        if (isT) {
            sTx[i] = pp.x; sTy[i] = pp.y; sTz[i] = pp.z; sTw[i] = pp.w; sTh[i] = ppsq;
            sMx[i] = m;
        } else {
            sRx[i] = pp.x; sRy[i] = pp.y; sRz[i] = pp.z; sRw[i] = pp.w; sRh[i] = ppsq;
            sMy[i] = m;
            sRn[i] = sqrtf(rawsq);
        }
        const unsigned long long bal = __ballot(m);   // waves 0..7 fully active here
        if ((t & 63) == 0) cnt[t >> 6] = (int)__popcll(bal);
    }
    __syncthreads();

    // ---- packed-math min passes: K=8 own rows x 16-wide scanned chunk ----
    {
        const bool pass1 = (t < 512);
        const int  u = pass1 ? t : (t - 512);
        const int  c = u >> 5;          // 0..15 scanned chunk (uniform per half-wave)
        const int  g = u & 31;          // own rows g + 32k, k=0..7
        const float* mx  = pass1 ? sTx : sRx;   // own planes
        const float* my  = pass1 ? sTy : sRy;
        const float* mz  = pass1 ? sTz : sRz;
        const float* mw  = pass1 ? sTw : sRw;
        const float* ox  = pass1 ? sRx : sTx;   // scanned planes
        const float* oy  = pass1 ? sRy : sTy;
        const float* oz  = pass1 ? sRz : sTz;
        const float* owp = pass1 ? sRw : sTw;
        float (*pout)[256] = pass1 ? pmin1 : pmin2;

        f2 n2x[8], n2y[8], n2z[8], n2w[8], mn[8];
        #pragma unroll
        for (int k = 0; k < 8; ++k) {
            const int row = g + (k << 5);
            n2x[k] = splat2(-2.f * mx[row]);
            n2y[k] = splat2(-2.f * my[row]);
            n2z[k] = splat2(-2.f * mz[row]);
            n2w[k] = splat2(-2.f * mw[row]);
            mn[k]  = splat2(MINSENT);
        }

        const int base = c << 4;        // 16-wide scanned chunk
        #pragma unroll
        for (int q = 0; q < 4; ++q) {   // 4 scanned points per iteration
            const int o = base + (q << 2);
            const float4 rx4 = *(const float4*)&ox[o];
            const float4 ry4 = *(const float4*)&oy[o];
            const float4 rz4 = *(const float4*)&oz[o];
            const float4 rw4 = *(const float4*)&owp[o];
            f2 rx0, rx1, ry0, ry1, rz0, rz1, rw0, rw1;
            rx0.x = rx4.x; rx0.y = rx4.y;  rx1.x = rx4.z; rx1.y = rx4.w;
            ry0.x = ry4.x; ry0.y = ry4.y;  ry1.x = ry4.z; ry1.y = ry4.w;
            rz0.x = rz4.x; rz0.y = rz4.y;  rz1.x = rz4.z; rz1.y = rz4.w;
            rw0.x = rw4.x; rw0.y = rw4.y;  rw1.x = rw4.z; rw1.y = rw4.w;
            // scan-side |y|^2, recomputed (cheaper than an LDS h-plane read)
            f2 rh0 = rx0 * rx0;
            rh0 = __builtin_elementwise_fma(ry0, ry0, rh0);
            rh0 = __builtin_elementwise_fma(rz0, rz0, rh0);
            rh0 = __builtin_elementwise_fma(rw0, rw0, rh0);
            f2 rh1 = rx1 * rx1;
            rh1 = __builtin_elementwise_fma(ry1, ry1, rh1);
            rh1 = __builtin_elementwise_fma(rz1, rz1, rh1);
            rh1 = __builtin_elementwise_fma(rw1, rw1, rh1);
            #pragma unroll
            for (int k = 0; k < 8; ++k) {
                // s = |y|^2 - 2 x.y   (own |x|^2 added once in the epilogue)
                f2 a0 = __builtin_elementwise_fma(n2x[k], rx0, rh0);
                a0 = __builtin_elementwise_fma(n2y[k], ry0, a0);
                a0 = __builtin_elementwise_fma(n2z[k], rz0, a0);
                a0 = __builtin_elementwise_fma(n2w[k], rw0, a0);
                mn[k] = __builtin_elementwise_min(mn[k], a0);
                f2 a1 = __builtin_elementwise_fma(n2x[k], rx1, rh1);
                a1 = __builtin_elementwise_fma(n2y[k], ry1, a1);
                a1 = __builtin_elementwise_fma(n2z[k], rz1, a1);
                a1 = __builtin_elementwise_fma(n2w[k], rw1, a1);
                mn[k] = __builtin_elementwise_min(mn[k], a1);
            }
        }
        #pragma unroll
        for (int k = 0; k < 8; ++k)
            pout[c][g + (k << 5)] = fminf(mn[k].x, mn[k].y);
    }
    __syncthreads();

    // ---- epilogue: 512 threads, one row/col each ----
    if (t < 512) {
        const bool rows = (t < 256);
        const int  i = rows ? t : (t - 256);
        float (*pm)[256] = rows ? pmin1 : pmin2;
        float m = pm[0][i];
        #pragma unroll
        for (int c2 = 1; c2 < 16; ++c2) m = fminf(m, pm[c2][i]);
        const float hrow = rows ? sTh[i] : sRh[i];
        m = fmaxf(hrow + m, 0.0f);                   // dist^2; guard rounding negatives
        const int msk = rows ? sMx[i] : sMy[i];
        float va, vb;
        if (rows) {
            va = msk ? sqrtf(m) : 0.f;               // -> sum_xy
            vb = msk ? sqrtf(sTh[i]) : 0.f;          // -> sum ||x|| over nonzero pid
        } else {
            va = msk ? sqrtf(m) : 0.f;               // -> sum_yx
            vb = msk ? 0.f : sRn[i];                 // -> sum ||y|| over zero pid
        }
        #pragma unroll
        for (int off = 32; off > 0; off >>= 1) {
            va += __shfl_down(va, off, 64);
            vb += __shfl_down(vb, off, 64);
        }
        if ((t & 63) == 0) {
            wred[t >> 6][0] = va;
            wred[t >> 6][1] = vb;
        }
    }
    __syncthreads();

    if (t == 0) {
        float s_xy = 0.f, s_nx = 0.f, s_yx = 0.f, s_ny0 = 0.f;
        int nx = 0, ny = 0;
        #pragma unroll
        for (int w = 0; w < 4; ++w) {
            s_xy  += wred[w][0];
            s_nx  += wred[w][1];
            s_yx  += wred[w + 4][0];
            s_ny0 += wred[w + 4][1];
            nx    += cnt[w];
            ny    += cnt[w + 4];
        }
        const float n_in  = (float)max(1, nx);
        const float n_out = (float)max(1, ny);
        const float normal = 0.5f * (s_xy / n_out + s_yx / n_in);
        const float eucl_nz = (ny == 0) ? (s_nx / n_in)
                                        : ((nx == 0) ? 0.0f : normal);
        const float n_zero = (float)max(1, MM - ny);
        const float eucl_z = s_ny0 / n_zero;
        ws[b] = make_float2(eucl_nz, eucl_z);   // plain store, no atomics
    }
}

// Kernel 2: one wave reduces 256 per-batch pairs; plain stores, no LDS/barrier.
__global__ __launch_bounds__(64) void chamfer_final_kernel(
    const float2* __restrict__ ws, float* __restrict__ out)
{
    const int t = threadIdx.x;   // 0..63
    float a = 0.f, z = 0.f;
    #pragma unroll
    for (int k = 0; k < 4; ++k) {
        const float2 v = ws[t + (k << 6)];
        a += v.x;
        z += v.y;
    }
    #pragma unroll
    for (int off = 32; off > 0; off >>= 1) {
        a += __shfl_down(a, off, 64);
        z += __shfl_down(z, off, 64);
    }
    if (t == 0) {
        out[0] = a * (1.0f / BB);
        out[1] = z * (1.0f / BB);
    }
}

extern "C" void kernel_launch(void* const* d_in, const int* in_sizes, int n_in,
                              void* d_out, int out_size, void* d_ws, size_t ws_size,
                              hipStream_t stream) {
    const float* target  = (const float*)d_in[0];
    const float* reco    = (const float*)d_in[1];
    const int*   in_pid  = (const int*)d_in[2];
    const int*   out_pid = (const int*)d_in[3];
    float* out = (float*)d_out;
    float2* ws = (float2*)d_ws;

    chamfer_batch_kernel<<<dim3(BB), dim3(1024), 0, stream>>>(
        target, reco, in_pid, out_pid, ws);
    chamfer_final_kernel<<<dim3(1), dim3(64), 0, stream>>>(ws, out);
}